// Round 23
// baseline (197.953 us; speedup 1.0000x reference)
//
#include <hip/hip_runtime.h>
#include <hip/hip_bf16.h>

typedef _Float16  f16x8  __attribute__((ext_vector_type(8)));
typedef float     f32x4  __attribute__((ext_vector_type(4)));
typedef unsigned short u16;
typedef u16       u16x4  __attribute__((ext_vector_type(4)));
typedef u16       u16x8  __attribute__((ext_vector_type(8)));

__device__ __forceinline__ u16 f2h_bits(float f) {
    union { _Float16 h; u16 u; } v; v.h = (_Float16)f; return v.u;
}

template<int N> __device__ __forceinline__ void vmwait() {
    if constexpr (N == 0)      asm volatile("s_waitcnt vmcnt(0)" ::: "memory");
    else if constexpr (N == 3) asm volatile("s_waitcnt vmcnt(3)" ::: "memory");
    else if constexpr (N == 4) asm volatile("s_waitcnt vmcnt(4)" ::: "memory");
    else if constexpr (N == 6) asm volatile("s_waitcnt vmcnt(6)" ::: "memory");
    else if constexpr (N == 8) asm volatile("s_waitcnt vmcnt(8)" ::: "memory");
}
__device__ __forceinline__ void pipe_barrier() {
    __builtin_amdgcn_s_barrier();
    __builtin_amdgcn_sched_barrier(0);
}

// ALL fp32->fp16 conversions (x + Wq|Wk|Wv stacked + W1 + W2) + bias concat, ONE dispatch.
__global__ __launch_bounds__(256)
void cvt_all(const float* __restrict__ x,
             const float* __restrict__ Wq, const float* __restrict__ Wk,
             const float* __restrict__ Wv, const float* __restrict__ W1,
             const float* __restrict__ W2, const float* __restrict__ bq,
             const float* __restrict__ bk, const float* __restrict__ bv,
             u16* __restrict__ x16, u16* __restrict__ Wqkv16,
             u16* __restrict__ W116, u16* __restrict__ W216, float* __restrict__ bqkv) {
    const int i = blockIdx.x * 256 + threadIdx.x;
    constexpr int X4 = 8192 * 512 / 4;
    constexpr int S = 512 * 512 / 4, L = 2048 * 512 / 4;
    const float* src; u16* dst; int j;
    if      (i < X4)                 { src = x;  dst = x16;            j = i;                  }
    else if (i < X4 + S)             { src = Wq; dst = Wqkv16;         j = i - X4;             }
    else if (i < X4 + 2 * S)         { src = Wk; dst = Wqkv16 + 4 * S; j = i - X4 - S;         }
    else if (i < X4 + 3 * S)         { src = Wv; dst = Wqkv16 + 8 * S; j = i - X4 - 2 * S;     }
    else if (i < X4 + 3 * S + L)     { src = W1; dst = W116;           j = i - X4 - 3 * S;     }
    else if (i < X4 + 3 * S + 2 * L) { src = W2; dst = W216;           j = i - X4 - 3 * S - L; }
    else if (i < X4 + 3 * S + 2 * L + 384) {
        const int g = (i - X4 - 3 * S - 2 * L) * 4;
#pragma unroll
        for (int t = 0; t < 4; ++t) {
            const int e = g + t;
            bqkv[e] = (e < 512) ? bq[e] : (e < 1024 ? bk[e - 512] : bv[e - 1024]);
        }
        return;
    } else return;
    f32x4 v = ((const f32x4*)src)[j];
    u16x4 h;
#pragma unroll
    for (int t = 0; t < 4; ++t) h[t] = f2h_bits(v[t]);
    ((u16x4*)dst)[j] = h;
}

// Stage a ROWSxCOLS 16-bit tile into LDS [ROWS][COLS] via global_load_lds dwordx4, with
// bank-conflict XOR swizzle applied via the GLOBAL source (LDS dest linear; rule 21).
// COLS=32: chunk cp of row holds global chunk cp^((row>>1)&3). COLS=64: cp^(row&7).
// NW waves cooperate.
template<int ROWS, int COLS, int NW>
__device__ __forceinline__ void stage_rows(const u16* __restrict__ g0, int ld, u16* lds, int wl) {
    const int l = threadIdx.x & 63;
    constexpr int CH = ROWS * COLS * 2 / 1024 / NW;
#pragma unroll
    for (int i = 0; i < CH; ++i) {
        const int base = (wl * CH + i) << 10;
        const int off  = base + (l << 4);
        const int row  = off / (COLS * 2);
        const int cp   = (off >> 4) & (COLS / 8 - 1);
        const int cs   = (COLS == 32) ? (cp ^ ((row >> 1) & 3)) : (cp ^ (row & 7));
        const u16* g = g0 + (size_t)row * ld + cs * 8;
        __builtin_amdgcn_global_load_lds((const __attribute__((address_space(1))) void*)g,
                                         (__attribute__((address_space(3))) void*)((char*)lds + base),
                                         16, 0, 0);
    }
}

// Swizzled fragment read: logical chunk lc of row lives at swizzled LDS chunk.
template<int COLS>
__device__ __forceinline__ f16x8 frag_read(const u16* tile, int row, int lc) {
    if constexpr (COLS == 32)
        return *(const f16x8*)&tile[row * 32 + ((lc ^ ((row >> 1) & 3)) << 3)];
    else
        return *(const f16x8*)&tile[row * 64 + ((lc ^ (row & 7)) << 3)];
}

// C[M,N] = A[M,K] @ B[N,K]^T (+bias). fp16 operands, fp32 accumulate.
// BM=128, BN in {64,128}, BK in {32,64}. PIPE=2: 2-slot dbuf + syncthreads.
// PIPE=3: 3-slot pipeline, counted vmcnt(LPT) + raw barrier (T3/T4).
// SPLITK=2: waves [0,4) K/2-low, [4,8) K/2-high (own slots), LDS-reduce at end.
// PVS: A is unnormalized P' = exp(s - m_b); per 64-K chunk fold tmp into acc scaled by
//      coefT[bz][cb][row] (prefetched f32x4 at chunk start).
// OMODE: 0 fp32 out; 2 fp16 out; 4 fused QKV (qk linear n<1024, vt transposed n>=1024);
//        5 P' fp16 out + per-(row,64col) max (xtra) and sumexp (xtra2).
template<int BN, int BK, int SPLITK, int PIPE, bool RELU, int OMODE, bool PVS, typename TC>
__global__ __launch_bounds__(256 * SPLITK,
                             (SPLITK == 2 && (BK == 64 || (PIPE == 3 && BN == 128))) ? 2
                                                                                    : 2 * SPLITK)
void gemm16(const u16* __restrict__ Ag, const u16* __restrict__ Bg,
            const float* __restrict__ bias, TC* __restrict__ C,
            void* __restrict__ xtra, const void* __restrict__ xtra2,
            int K, int lda, int ldb, int ldc,
            long sA, long sB, long sC)
{
    // XCD-aware bijective swizzle (all grids have nwg % 8 == 0).
    const int nx = gridDim.x, ny = gridDim.y;
    const int nwg = nx * ny * gridDim.z;
    int bid = blockIdx.x + nx * (blockIdx.y + ny * blockIdx.z);
    int swz = (bid & 7) * (nwg >> 3) + (bid >> 3);
    const int n0 = (swz % nx) * BN; swz /= nx;
    const int m0 = (swz % ny) * 128;
    const int bz = swz / ny;

    constexpr int FR = (BN == 128) ? 4 : 2;      // 16-row A-fragments per wave
    constexpr int ATILE = 128 * BK;
    constexpr int BTILE = BN * BK;
    constexpr int BUFSZ = ATILE + BTILE;
    constexpr int LPT = (128 + BN) * BK * 2 / 1024 / 4;  // gloads per thread per tile
    __shared__ __align__(16) u16 smem[SPLITK * PIPE * BUFSZ];

    const int l  = threadIdx.x & 63, w = threadIdx.x >> 6;
    const int kw = (SPLITK == 2) ? (w >> 2) : 0;
    const int wl = w & 3;
    const int wr = (BN == 128) ? (wl >> 1) * 64 : wl * 32;
    const int wc = (BN == 128) ? (wl & 1) * 64 : 0;
    const int lr = l & 15, kg = l >> 4;

    const int Kh = K / SPLITK;
    const int kb = kw * Kh;
    const int T  = Kh / BK;

    const u16* Ab = Ag + (size_t)bz * sA + (size_t)m0 * lda + kb;
    const u16* Bb = Bg + (size_t)bz * sB + (size_t)n0 * ldb + kb;
    const float* Cb = PVS ? ((const float*)xtra2 + (size_t)bz * 32 * 2048) : nullptr;
    C += (size_t)bz * sC;

    u16* mybuf = smem + kw * PIPE * BUFSZ;

    auto stage = [&](int slot, int t) {
        u16* s = mybuf + slot * BUFSZ;
        stage_rows<128, BK, 4>(Ab + t * BK, lda, s, wl);
        stage_rows<BN, BK, 4>(Bb + t * BK, ldb, s + ATILE, wl);
    };

    f32x4 acc[FR][4] = {};
    f32x4 tmp[FR][4] = {};
    f32x4 cfp[FR];
    auto compute = [&](int slot) {
        const u16* sA = mybuf + slot * BUFSZ;
        const u16* sB = sA + ATILE;
        constexpr int NSUB = BK / 32;
#pragma unroll
        for (int sub = 0; sub < NSUB; ++sub) {
            f16x8 a[FR], b[4];
#pragma unroll
            for (int i = 0; i < FR; ++i) a[i] = frag_read<BK>(sA, wr + i * 16 + lr, sub * 4 + kg);
#pragma unroll
            for (int i = 0; i < 4; ++i)  b[i] = frag_read<BK>(sB, wc + i * 16 + lr, sub * 4 + kg);
#pragma unroll
            for (int mi = 0; mi < FR; ++mi)
#pragma unroll
                for (int ni = 0; ni < 4; ++ni) {
                    if constexpr (PVS)
                        tmp[mi][ni] = __builtin_amdgcn_mfma_f32_16x16x32_f16(a[mi], b[ni], tmp[mi][ni], 0, 0, 0);
                    else
                        acc[mi][ni] = __builtin_amdgcn_mfma_f32_16x16x32_f16(a[mi], b[ni], acc[mi][ni], 0, 0, 0);
                }
        }
    };
    auto pvs_pre = [&](int t) {
        if constexpr (PVS) {
            if (BK == 64 || (t & 1) == 0) {      // 64-K chunk start: prefetch coef
                const int cb = (kb + t * BK) >> 6;
#pragma unroll
                for (int mi = 0; mi < FR; ++mi)
                    cfp[mi] = *(const f32x4*)&Cb[(size_t)cb * 2048 + (m0 + wr + mi * 16 + kg * 4)];
            }
        }
    };
    auto pvs_post = [&](int t) {
        if constexpr (PVS) {
            if (BK == 64 || (t & 1)) {           // 64-K chunk end: fold with prefetched coef
#pragma unroll
                for (int mi = 0; mi < FR; ++mi)
#pragma unroll
                    for (int ni = 0; ni < 4; ++ni) {
#pragma unroll
                        for (int j = 0; j < 4; ++j) acc[mi][ni][j] += cfp[mi][j] * tmp[mi][ni][j];
                        tmp[mi][ni] = f32x4{0.f, 0.f, 0.f, 0.f};
                    }
            }
        }
    };

    if constexpr (PIPE == 3) {
        stage(0, 0);
        stage(1, 1);
        vmwait<LPT>();                           // tile 0 resident, tile 1 in flight
        pipe_barrier();
        for (int t = 0; t < T; ++t) {
            pvs_pre(t);
            if (t + 2 < T) stage((t + 2) % 3, t + 2);
            compute(t % 3);
            pvs_post(t);
            if (t + 2 < T) vmwait<LPT>();        // tile t+1 resident, t+2 in flight
            else           vmwait<0>();
            pipe_barrier();
        }
    } else {
        stage(0, 0);
        __syncthreads();
        int cur = 0;
        for (int t = 0; t < T; ++t) {
            if (t + 1 < T) stage(cur ^ 1, t + 1);
            pvs_pre(t);
            compute(cur);
            pvs_post(t);
            __syncthreads();
            cur ^= 1;
        }
    }

    if constexpr (SPLITK == 2) {
        float* red = (float*)smem;
        const int slot = (wl * 64 + l) * (FR * 4);
        if (kw == 1) {
#pragma unroll
            for (int mi = 0; mi < FR; ++mi)
#pragma unroll
                for (int ni = 0; ni < 4; ++ni)
                    *(f32x4*)&red[(slot + mi * 4 + ni) * 4] = acc[mi][ni];
        }
        __syncthreads();
        if (kw == 1) return;
#pragma unroll
        for (int mi = 0; mi < FR; ++mi)
#pragma unroll
            for (int ni = 0; ni < 4; ++ni)
                acc[mi][ni] += *(const f32x4*)&red[(slot + mi * 4 + ni) * 4];
    }

    if constexpr (OMODE == 5) {
        float* MB = (float*)xtra + (size_t)bz * 2048 * 32;
        float* SB = (float*)const_cast<void*>(xtra2);
        SB += (size_t)bz * 2048 * 32;
        const int cb = (n0 + wc) >> 6;
#pragma unroll
        for (int mi = 0; mi < FR; ++mi) {
            const int mbase = m0 + wr + mi * 16 + kg * 4;
#pragma unroll
            for (int j = 0; j < 4; ++j) {
                float rmax = fmaxf(fmaxf(acc[mi][0][j], acc[mi][1][j]),
                                   fmaxf(acc[mi][2][j], acc[mi][3][j]));
                rmax = fmaxf(rmax, __shfl_xor(rmax, 1));
                rmax = fmaxf(rmax, __shfl_xor(rmax, 2));
                rmax = fmaxf(rmax, __shfl_xor(rmax, 4));
                rmax = fmaxf(rmax, __shfl_xor(rmax, 8));
                float p[4]; float lsum = 0.0f;
#pragma unroll
                for (int ni = 0; ni < 4; ++ni) { p[ni] = __expf(acc[mi][ni][j] - rmax); lsum += p[ni]; }
                lsum += __shfl_xor(lsum, 1);
                lsum += __shfl_xor(lsum, 2);
                lsum += __shfl_xor(lsum, 4);
                lsum += __shfl_xor(lsum, 8);
                const int row = mbase + j;
                if (lr == 0) {
                    MB[(size_t)row * 32 + cb] = rmax;
                    SB[(size_t)row * 32 + cb] = lsum;
                }
#pragma unroll
                for (int ni = 0; ni < 4; ++ni)
                    ((u16*)C)[(size_t)row * ldc + (n0 + wc + ni * 16 + lr)] = f2h_bits(p[ni]);
            }
        }
        return;
    }

#pragma unroll
    for (int mi = 0; mi < FR; ++mi) {
        const int mbase = m0 + wr + mi * 16 + kg * 4;
#pragma unroll
        for (int ni = 0; ni < 4; ++ni) {
            const int n = n0 + wc + ni * 16 + lr;
            const float bv = bias ? bias[n] : 0.0f;
            if constexpr (OMODE == 4) {
                if (n0 < 1024) {        // q|k region, fp16 linear [8192][1024]
#pragma unroll
                    for (int j = 0; j < 4; ++j)
                        ((u16*)C)[(size_t)(mbase + j) * ldc + n] = f2h_bits(acc[mi][ni][j] + bv);
                } else {                // v region, transposed vt[4][512][2048]
                    const int d  = n - 1024;
                    const int bb = mbase >> 11;
                    const int s  = mbase & 2047;
                    u16x4 o;
#pragma unroll
                    for (int j = 0; j < 4; ++j) o[j] = f2h_bits(acc[mi][ni][j] + bv);
                    *(u16x4*)((u16*)xtra + ((size_t)bb * 512 + d) * 2048 + s) = o;
                }
            } else {
#pragma unroll
                for (int j = 0; j < 4; ++j) {
                    float x = acc[mi][ni][j] + bv;
                    if constexpr (RELU) x = fmaxf(x, 0.0f);
                    const size_t idx = (size_t)(mbase + j) * ldc + n;
                    if constexpr (OMODE == 0) C[idx] = x;
                    else                      ((u16*)C)[idx] = f2h_bits(x);
                }
            }
        }
    }
}

// Per-row softmax stats -> TRANSPOSED coef: Cf[bz][cb][row] = exp(mb-m)/Z.
__global__ __launch_bounds__(256)
void softmax_stats(const float* __restrict__ MB, const float* __restrict__ SB,
                   float* __restrict__ Cf) {
    const int row = blockIdx.x * 256 + threadIdx.x;      // 8192 rows
    const f32x4* mbp = (const f32x4*)(MB + (size_t)row * 32);
    const f32x4* sbp = (const f32x4*)(SB + (size_t)row * 32);
    f32x4 mv[8], sv[8];
#pragma unroll
    for (int i = 0; i < 8; ++i) { mv[i] = mbp[i]; sv[i] = sbp[i]; }
    float m = mv[0][0];
#pragma unroll
    for (int i = 0; i < 8; ++i)
#pragma unroll
        for (int j = 0; j < 4; ++j) m = fmaxf(m, mv[i][j]);
    float e[8][4]; float s = 0.0f;
#pragma unroll
    for (int i = 0; i < 8; ++i)
#pragma unroll
        for (int j = 0; j < 4; ++j) { e[i][j] = __expf(mv[i][j] - m); s += sv[i][j] * e[i][j]; }
    const float inv = 1.0f / s;
    const int bz = row >> 11, sr = row & 2047;
    float* cp = Cf + (size_t)bz * 32 * 2048 + sr;
#pragma unroll
    for (int i = 0; i < 8; ++i)
#pragma unroll
        for (int j = 0; j < 4; ++j) cp[(size_t)(i * 4 + j) * 2048] = e[i][j] * inv;
}

extern "C" void kernel_launch(void* const* d_in, const int* in_sizes, int n_in,
                              void* d_out, int out_size, void* d_ws, size_t ws_size,
                              hipStream_t stream) {
    const float* x  = (const float*)d_in[0];
    const float* Wq = (const float*)d_in[1];
    const float* bq = (const float*)d_in[2];
    const float* Wk = (const float*)d_in[3];
    const float* bk = (const float*)d_in[4];
    const float* Wv = (const float*)d_in[5];
    const float* bv = (const float*)d_in[6];
    const float* W1 = (const float*)d_in[7];
    const float* b1 = (const float*)d_in[8];
    const float* W2 = (const float*)d_in[9];
    const float* b2 = (const float*)d_in[10];
    float* out = (float*)d_out;

    char* ws = (char*)d_ws;
    size_t off = 0;
    auto alloc = [&](size_t bytes) { void* p = ws + off; off += (bytes + 255) & ~(size_t)255; return p; };
    u16* x16    = (u16*)alloc(8192ull * 512 * 2);        //  8.4 MB; attn overlays later
    u16* Wqkv16 = (u16*)alloc(1536ull * 512 * 2);
    u16* W116   = (u16*)alloc(2048ull * 512 * 2);
    u16* W216   = (u16*)alloc(512ull * 2048 * 2);
    float* bqkv = (float*)alloc(1536 * 4);
    u16* qk     = (u16*)alloc(8192ull * 1024 * 2);       // 16.8 MB fp16 [8192][1024]
    u16* p16    = (u16*)alloc(4ull * 2048 * 2048 * 2);   // 33.6 MB unnormalized P'; h overlays
    u16* vt     = (u16*)alloc(4ull * 512 * 2048 * 2);    //  8.4 MB fp16 [b][d][s]
    float* mb   = (float*)alloc(8192ull * 32 * 4);       //  1 MB per-(row,64col) max
    float* sb   = (float*)alloc(8192ull * 32 * 4);       //  1 MB per-(row,64col) sumexp
    float* cf   = (float*)alloc(8192ull * 32 * 4);       //  1 MB coef, TRANSPOSED [bz][cb][row]
    u16* attn = x16;                    // fp16 [8192][512]; x dead after projections
    u16* h    = p16;                    // fp16 [8192][2048]; P' dead after PV
    if (ws_size < off) return;

    dim3 blk(256), blk2(512);

    cvt_all<<<dim3(6914), blk, 0, stream>>>(x, Wq, Wk, Wv, W1, W2, bq, bk, bv,
                                            x16, Wqkv16, W116, W216, bqkv);

    // [q|k|vt] = x @ [Wq;Wk;Wv]^T + b    768 blocks, 128x128x32, PIPE2
    gemm16<128, 32, 1, 2, false, 4, false, u16><<<dim3(12, 64, 1), blk, 0, stream>>>(
        x16, Wqkv16, bqkv, qk, vt, nullptr, 512, 512, 512, 1024, 0, 0, 0);
    // P'[b] = exp(q@k^T - m_b) -> fp16 + mb + sb   1024 blocks, 128x128x32, splitK=2, T=8
    gemm16<128, 32, 2, 2, false, 5, false, u16><<<dim3(16, 16, 4), blk2, 0, stream>>>(
        qk, qk + 512, nullptr, p16, mb, sb, 512, 1024, 1024, 2048,
        2048L * 1024, 2048L * 1024, 2048L * 2048);
    // per-row softmax coefficients (transposed)              32 blocks
    softmax_stats<<<dim3(32), blk, 0, stream>>>(mb, sb, cf);
    // attn[b] = sum_cb coef * (P'_cb @ V_cb)      256 blocks, 128x128x64, splitK=2, T=16
    gemm16<128, 64, 2, 2, false, 2, true, u16><<<dim3(4, 16, 4), blk2, 0, stream>>>(
        p16, vt, nullptr, attn, nullptr, cf, 2048, 2048, 2048, 512,
        2048L * 2048, 512L * 2048, 2048L * 512);
    // h = relu(attn @ W1^T + b1)                  1024 blocks, 128x128x32, splitK=2, T=8
    gemm16<128, 32, 2, 2, true, 2, false, u16><<<dim3(16, 64, 1), blk2, 0, stream>>>(
        attn, W116, b1, h, nullptr, nullptr, 512, 512, 512, 2048, 0, 0, 0);
    // out = h @ W2^T + b2                          256 blocks, 128x128x64, splitK=2, T=16
    gemm16<128, 64, 2, 2, false, 0, false, float><<<dim3(4, 64, 1), blk2, 0, stream>>>(
        h, W216, b2, out, nullptr, nullptr, 2048, 2048, 2048, 512, 0, 0, 0);
}

// Round 24
// 161.326 us; speedup vs baseline: 1.2270x; 1.2270x over previous
//
#include <hip/hip_runtime.h>
#include <hip/hip_bf16.h>

typedef _Float16  f16x8  __attribute__((ext_vector_type(8)));
typedef float     f32x4  __attribute__((ext_vector_type(4)));
typedef unsigned short u16;
typedef u16       u16x4  __attribute__((ext_vector_type(4)));
typedef u16       u16x8  __attribute__((ext_vector_type(8)));

__device__ __forceinline__ u16 f2h_bits(float f) {
    union { _Float16 h; u16 u; } v; v.h = (_Float16)f; return v.u;
}

template<int N> __device__ __forceinline__ void vmwait() {
    if constexpr (N == 0)      asm volatile("s_waitcnt vmcnt(0)" ::: "memory");
    else if constexpr (N == 3) asm volatile("s_waitcnt vmcnt(3)" ::: "memory");
    else if constexpr (N == 4) asm volatile("s_waitcnt vmcnt(4)" ::: "memory");
    else if constexpr (N == 6) asm volatile("s_waitcnt vmcnt(6)" ::: "memory");
    else if constexpr (N == 8) asm volatile("s_waitcnt vmcnt(8)" ::: "memory");
}
__device__ __forceinline__ void pipe_barrier() {
    __builtin_amdgcn_s_barrier();
    __builtin_amdgcn_sched_barrier(0);
}

// ALL fp32->fp16 conversions (x + Wq|Wk|Wv stacked + W1 + W2) + bias concat, ONE dispatch.
__global__ __launch_bounds__(256)
void cvt_all(const float* __restrict__ x,
             const float* __restrict__ Wq, const float* __restrict__ Wk,
             const float* __restrict__ Wv, const float* __restrict__ W1,
             const float* __restrict__ W2, const float* __restrict__ bq,
             const float* __restrict__ bk, const float* __restrict__ bv,
             u16* __restrict__ x16, u16* __restrict__ Wqkv16,
             u16* __restrict__ W116, u16* __restrict__ W216, float* __restrict__ bqkv) {
    const int i = blockIdx.x * 256 + threadIdx.x;
    constexpr int X4 = 8192 * 512 / 4;
    constexpr int S = 512 * 512 / 4, L = 2048 * 512 / 4;
    const float* src; u16* dst; int j;
    if      (i < X4)                 { src = x;  dst = x16;            j = i;                  }
    else if (i < X4 + S)             { src = Wq; dst = Wqkv16;         j = i - X4;             }
    else if (i < X4 + 2 * S)         { src = Wk; dst = Wqkv16 + 4 * S; j = i - X4 - S;         }
    else if (i < X4 + 3 * S)         { src = Wv; dst = Wqkv16 + 8 * S; j = i - X4 - 2 * S;     }
    else if (i < X4 + 3 * S + L)     { src = W1; dst = W116;           j = i - X4 - 3 * S;     }
    else if (i < X4 + 3 * S + 2 * L) { src = W2; dst = W216;           j = i - X4 - 3 * S - L; }
    else if (i < X4 + 3 * S + 2 * L + 384) {
        const int g = (i - X4 - 3 * S - 2 * L) * 4;
#pragma unroll
        for (int t = 0; t < 4; ++t) {
            const int e = g + t;
            bqkv[e] = (e < 512) ? bq[e] : (e < 1024 ? bk[e - 512] : bv[e - 1024]);
        }
        return;
    } else return;
    f32x4 v = ((const f32x4*)src)[j];
    u16x4 h;
#pragma unroll
    for (int t = 0; t < 4; ++t) h[t] = f2h_bits(v[t]);
    ((u16x4*)dst)[j] = h;
}

// Stage a ROWSxCOLS 16-bit tile into LDS [ROWS][COLS] via global_load_lds dwordx4, with
// bank-conflict XOR swizzle applied via the GLOBAL source (LDS dest linear; rule 21).
// COLS=32: chunk cp of row holds global chunk cp^((row>>1)&3). COLS=64: cp^(row&7).
// NW waves cooperate.
template<int ROWS, int COLS, int NW>
__device__ __forceinline__ void stage_rows(const u16* __restrict__ g0, int ld, u16* lds, int wl) {
    const int l = threadIdx.x & 63;
    constexpr int CH = ROWS * COLS * 2 / 1024 / NW;
#pragma unroll
    for (int i = 0; i < CH; ++i) {
        const int base = (wl * CH + i) << 10;
        const int off  = base + (l << 4);
        const int row  = off / (COLS * 2);
        const int cp   = (off >> 4) & (COLS / 8 - 1);
        const int cs   = (COLS == 32) ? (cp ^ ((row >> 1) & 3)) : (cp ^ (row & 7));
        const u16* g = g0 + (size_t)row * ld + cs * 8;
        __builtin_amdgcn_global_load_lds((const __attribute__((address_space(1))) void*)g,
                                         (__attribute__((address_space(3))) void*)((char*)lds + base),
                                         16, 0, 0);
    }
}

// Swizzled fragment read: logical chunk lc of row lives at swizzled LDS chunk.
template<int COLS>
__device__ __forceinline__ f16x8 frag_read(const u16* tile, int row, int lc) {
    if constexpr (COLS == 32)
        return *(const f16x8*)&tile[row * 32 + ((lc ^ ((row >> 1) & 3)) << 3)];
    else
        return *(const f16x8*)&tile[row * 64 + ((lc ^ (row & 7)) << 3)];
}

// C[M,N] = A[M,K] @ B[N,K]^T (+bias). fp16 operands, fp32 accumulate.
// BM=128, BN in {64,128}, BK in {32,64}. PIPE=2: 2-slot dbuf + syncthreads.
// PIPE=3: 3-slot pipeline, counted vmcnt(LPT) + raw barrier (T3/T4).
// SPLITK=2: waves [0,4) K/2-low, [4,8) K/2-high (own slots), LDS-reduce at end.
// PVS: A is unnormalized P' = exp(s - m_b); per 64-K chunk fold tmp into acc scaled by
//      coefT[bz][cb][row] (prefetched f32x4 at chunk start).
// OMODE: 0 fp32 out; 2 fp16 out; 4 fused QKV (qk linear n<1024, vt transposed n>=1024);
//        5 P' fp16 out + per-(row,64col) max (xtra) and sumexp (xtra2).
template<int BN, int BK, int SPLITK, int PIPE, bool RELU, int OMODE, bool PVS, typename TC>
__global__ __launch_bounds__(256 * SPLITK,
                             (SPLITK == 2 && (BK == 64 || (PIPE == 3 && BN == 128))) ? 2
                                                                                    : 2 * SPLITK)
void gemm16(const u16* __restrict__ Ag, const u16* __restrict__ Bg,
            const float* __restrict__ bias, TC* __restrict__ C,
            void* __restrict__ xtra, const void* __restrict__ xtra2,
            int K, int lda, int ldb, int ldc,
            long sA, long sB, long sC)
{
    // XCD-aware bijective swizzle (all grids have nwg % 8 == 0).
    const int nx = gridDim.x, ny = gridDim.y;
    const int nwg = nx * ny * gridDim.z;
    int bid = blockIdx.x + nx * (blockIdx.y + ny * blockIdx.z);
    int swz = (bid & 7) * (nwg >> 3) + (bid >> 3);
    const int n0 = (swz % nx) * BN; swz /= nx;
    const int m0 = (swz % ny) * 128;
    const int bz = swz / ny;

    constexpr int FR = (BN == 128) ? 4 : 2;      // 16-row A-fragments per wave
    constexpr int ATILE = 128 * BK;
    constexpr int BTILE = BN * BK;
    constexpr int BUFSZ = ATILE + BTILE;
    constexpr int LPT = (128 + BN) * BK * 2 / 1024 / 4;  // gloads per thread per tile
    __shared__ __align__(16) u16 smem[SPLITK * PIPE * BUFSZ];

    const int l  = threadIdx.x & 63, w = threadIdx.x >> 6;
    const int kw = (SPLITK == 2) ? (w >> 2) : 0;
    const int wl = w & 3;
    const int wr = (BN == 128) ? (wl >> 1) * 64 : wl * 32;
    const int wc = (BN == 128) ? (wl & 1) * 64 : 0;
    const int lr = l & 15, kg = l >> 4;

    const int Kh = K / SPLITK;
    const int kb = kw * Kh;
    const int T  = Kh / BK;

    const u16* Ab = Ag + (size_t)bz * sA + (size_t)m0 * lda + kb;
    const u16* Bb = Bg + (size_t)bz * sB + (size_t)n0 * ldb + kb;
    const float* Cb = PVS ? ((const float*)xtra2 + (size_t)bz * 32 * 2048) : nullptr;
    C += (size_t)bz * sC;

    u16* mybuf = smem + kw * PIPE * BUFSZ;

    auto stage = [&](int slot, int t) {
        u16* s = mybuf + slot * BUFSZ;
        stage_rows<128, BK, 4>(Ab + t * BK, lda, s, wl);
        stage_rows<BN, BK, 4>(Bb + t * BK, ldb, s + ATILE, wl);
    };

    f32x4 acc[FR][4] = {};
    f32x4 tmp[FR][4] = {};
    f32x4 cfp[FR];
    auto compute = [&](int slot) {
        const u16* sA = mybuf + slot * BUFSZ;
        const u16* sB = sA + ATILE;
        constexpr int NSUB = BK / 32;
#pragma unroll
        for (int sub = 0; sub < NSUB; ++sub) {
            f16x8 a[FR], b[4];
#pragma unroll
            for (int i = 0; i < FR; ++i) a[i] = frag_read<BK>(sA, wr + i * 16 + lr, sub * 4 + kg);
#pragma unroll
            for (int i = 0; i < 4; ++i)  b[i] = frag_read<BK>(sB, wc + i * 16 + lr, sub * 4 + kg);
#pragma unroll
            for (int mi = 0; mi < FR; ++mi)
#pragma unroll
                for (int ni = 0; ni < 4; ++ni) {
                    if constexpr (PVS)
                        tmp[mi][ni] = __builtin_amdgcn_mfma_f32_16x16x32_f16(a[mi], b[ni], tmp[mi][ni], 0, 0, 0);
                    else
                        acc[mi][ni] = __builtin_amdgcn_mfma_f32_16x16x32_f16(a[mi], b[ni], acc[mi][ni], 0, 0, 0);
                }
        }
    };
    auto pvs_pre = [&](int t) {
        if constexpr (PVS) {
            if (BK == 64 || (t & 1) == 0) {      // 64-K chunk start: prefetch coef
                const int cb = (kb + t * BK) >> 6;
#pragma unroll
                for (int mi = 0; mi < FR; ++mi)
                    cfp[mi] = *(const f32x4*)&Cb[(size_t)cb * 2048 + (m0 + wr + mi * 16 + kg * 4)];
            }
        }
    };
    auto pvs_post = [&](int t) {
        if constexpr (PVS) {
            if (BK == 64 || (t & 1)) {           // 64-K chunk end: fold with prefetched coef
#pragma unroll
                for (int mi = 0; mi < FR; ++mi)
#pragma unroll
                    for (int ni = 0; ni < 4; ++ni) {
#pragma unroll
                        for (int j = 0; j < 4; ++j) acc[mi][ni][j] += cfp[mi][j] * tmp[mi][ni][j];
                        tmp[mi][ni] = f32x4{0.f, 0.f, 0.f, 0.f};
                    }
            }
        }
    };

    if constexpr (PIPE == 3) {
        stage(0, 0);
        stage(1, 1);
        vmwait<LPT>();                           // tile 0 resident, tile 1 in flight
        pipe_barrier();
        for (int t = 0; t < T; ++t) {
            pvs_pre(t);
            if (t + 2 < T) stage((t + 2) % 3, t + 2);
            compute(t % 3);
            pvs_post(t);
            if (t + 2 < T) vmwait<LPT>();        // tile t+1 resident, t+2 in flight
            else           vmwait<0>();
            pipe_barrier();
        }
    } else {
        stage(0, 0);
        __syncthreads();
        int cur = 0;
        for (int t = 0; t < T; ++t) {
            if (t + 1 < T) stage(cur ^ 1, t + 1);
            pvs_pre(t);
            compute(cur);
            pvs_post(t);
            __syncthreads();
            cur ^= 1;
        }
    }

    if constexpr (SPLITK == 2) {
        float* red = (float*)smem;
        const int slot = (wl * 64 + l) * (FR * 4);
        if (kw == 1) {
#pragma unroll
            for (int mi = 0; mi < FR; ++mi)
#pragma unroll
                for (int ni = 0; ni < 4; ++ni)
                    *(f32x4*)&red[(slot + mi * 4 + ni) * 4] = acc[mi][ni];
        }
        __syncthreads();
        if (kw == 1) return;
#pragma unroll
        for (int mi = 0; mi < FR; ++mi)
#pragma unroll
            for (int ni = 0; ni < 4; ++ni)
                acc[mi][ni] += *(const f32x4*)&red[(slot + mi * 4 + ni) * 4];
    }

    if constexpr (OMODE == 5) {
        float* MB = (float*)xtra + (size_t)bz * 2048 * 32;
        float* SB = (float*)const_cast<void*>(xtra2);
        SB += (size_t)bz * 2048 * 32;
        const int cb = (n0 + wc) >> 6;
#pragma unroll
        for (int mi = 0; mi < FR; ++mi) {
            const int mbase = m0 + wr + mi * 16 + kg * 4;
#pragma unroll
            for (int j = 0; j < 4; ++j) {
                float rmax = fmaxf(fmaxf(acc[mi][0][j], acc[mi][1][j]),
                                   fmaxf(acc[mi][2][j], acc[mi][3][j]));
                rmax = fmaxf(rmax, __shfl_xor(rmax, 1));
                rmax = fmaxf(rmax, __shfl_xor(rmax, 2));
                rmax = fmaxf(rmax, __shfl_xor(rmax, 4));
                rmax = fmaxf(rmax, __shfl_xor(rmax, 8));
                float p[4]; float lsum = 0.0f;
#pragma unroll
                for (int ni = 0; ni < 4; ++ni) { p[ni] = __expf(acc[mi][ni][j] - rmax); lsum += p[ni]; }
                lsum += __shfl_xor(lsum, 1);
                lsum += __shfl_xor(lsum, 2);
                lsum += __shfl_xor(lsum, 4);
                lsum += __shfl_xor(lsum, 8);
                const int row = mbase + j;
                if (lr == 0) {
                    MB[(size_t)row * 32 + cb] = rmax;
                    SB[(size_t)row * 32 + cb] = lsum;
                }
#pragma unroll
                for (int ni = 0; ni < 4; ++ni)
                    ((u16*)C)[(size_t)row * ldc + (n0 + wc + ni * 16 + lr)] = f2h_bits(p[ni]);
            }
        }
        return;
    }

#pragma unroll
    for (int mi = 0; mi < FR; ++mi) {
        const int mbase = m0 + wr + mi * 16 + kg * 4;
#pragma unroll
        for (int ni = 0; ni < 4; ++ni) {
            const int n = n0 + wc + ni * 16 + lr;
            const float bv = bias ? bias[n] : 0.0f;
            if constexpr (OMODE == 4) {
                if (n0 < 1024) {        // q|k region, fp16 linear [8192][1024]
#pragma unroll
                    for (int j = 0; j < 4; ++j)
                        ((u16*)C)[(size_t)(mbase + j) * ldc + n] = f2h_bits(acc[mi][ni][j] + bv);
                } else {                // v region, transposed vt[4][512][2048]
                    const int d  = n - 1024;
                    const int bb = mbase >> 11;
                    const int s  = mbase & 2047;
                    u16x4 o;
#pragma unroll
                    for (int j = 0; j < 4; ++j) o[j] = f2h_bits(acc[mi][ni][j] + bv);
                    *(u16x4*)((u16*)xtra + ((size_t)bb * 512 + d) * 2048 + s) = o;
                }
            } else {
#pragma unroll
                for (int j = 0; j < 4; ++j) {
                    float x = acc[mi][ni][j] + bv;
                    if constexpr (RELU) x = fmaxf(x, 0.0f);
                    const size_t idx = (size_t)(mbase + j) * ldc + n;
                    if constexpr (OMODE == 0) C[idx] = x;
                    else                      ((u16*)C)[idx] = f2h_bits(x);
                }
            }
        }
    }
}

// Per-row softmax stats -> TRANSPOSED coef: Cf[bz][cb][row] = exp(mb-m)/Z.
__global__ __launch_bounds__(256)
void softmax_stats(const float* __restrict__ MB, const float* __restrict__ SB,
                   float* __restrict__ Cf) {
    const int row = blockIdx.x * 256 + threadIdx.x;      // 8192 rows
    const f32x4* mbp = (const f32x4*)(MB + (size_t)row * 32);
    const f32x4* sbp = (const f32x4*)(SB + (size_t)row * 32);
    f32x4 mv[8], sv[8];
#pragma unroll
    for (int i = 0; i < 8; ++i) { mv[i] = mbp[i]; sv[i] = sbp[i]; }
    float m = mv[0][0];
#pragma unroll
    for (int i = 0; i < 8; ++i)
#pragma unroll
        for (int j = 0; j < 4; ++j) m = fmaxf(m, mv[i][j]);
    float e[8][4]; float s = 0.0f;
#pragma unroll
    for (int i = 0; i < 8; ++i)
#pragma unroll
        for (int j = 0; j < 4; ++j) { e[i][j] = __expf(mv[i][j] - m); s += sv[i][j] * e[i][j]; }
    const float inv = 1.0f / s;
    const int bz = row >> 11, sr = row & 2047;
    float* cp = Cf + (size_t)bz * 32 * 2048 + sr;
#pragma unroll
    for (int i = 0; i < 8; ++i)
#pragma unroll
        for (int j = 0; j < 4; ++j) cp[(size_t)(i * 4 + j) * 2048] = e[i][j] * inv;
}

extern "C" void kernel_launch(void* const* d_in, const int* in_sizes, int n_in,
                              void* d_out, int out_size, void* d_ws, size_t ws_size,
                              hipStream_t stream) {
    const float* x  = (const float*)d_in[0];
    const float* Wq = (const float*)d_in[1];
    const float* bq = (const float*)d_in[2];
    const float* Wk = (const float*)d_in[3];
    const float* bk = (const float*)d_in[4];
    const float* Wv = (const float*)d_in[5];
    const float* bv = (const float*)d_in[6];
    const float* W1 = (const float*)d_in[7];
    const float* b1 = (const float*)d_in[8];
    const float* W2 = (const float*)d_in[9];
    const float* b2 = (const float*)d_in[10];
    float* out = (float*)d_out;

    char* ws = (char*)d_ws;
    size_t off = 0;
    auto alloc = [&](size_t bytes) { void* p = ws + off; off += (bytes + 255) & ~(size_t)255; return p; };
    u16* x16    = (u16*)alloc(8192ull * 512 * 2);        //  8.4 MB; attn overlays later
    u16* Wqkv16 = (u16*)alloc(1536ull * 512 * 2);
    u16* W116   = (u16*)alloc(2048ull * 512 * 2);
    u16* W216   = (u16*)alloc(512ull * 2048 * 2);
    float* bqkv = (float*)alloc(1536 * 4);
    u16* qk     = (u16*)alloc(8192ull * 1024 * 2);       // 16.8 MB fp16 [8192][1024]
    u16* p16    = (u16*)alloc(4ull * 2048 * 2048 * 2);   // 33.6 MB unnormalized P'; h overlays
    u16* vt     = (u16*)alloc(4ull * 512 * 2048 * 2);    //  8.4 MB fp16 [b][d][s]
    float* mb   = (float*)alloc(8192ull * 32 * 4);       //  1 MB per-(row,64col) max
    float* sb   = (float*)alloc(8192ull * 32 * 4);       //  1 MB per-(row,64col) sumexp
    float* cf   = (float*)alloc(8192ull * 32 * 4);       //  1 MB coef, TRANSPOSED [bz][cb][row]
    u16* attn = x16;                    // fp16 [8192][512]; x dead after projections
    u16* h    = p16;                    // fp16 [8192][2048]; P' dead after PV
    if (ws_size < off) return;

    dim3 blk(256), blk2(512);

    cvt_all<<<dim3(6914), blk, 0, stream>>>(x, Wq, Wk, Wv, W1, W2, bq, bk, bv,
                                            x16, Wqkv16, W116, W216, bqkv);

    // [q|k|vt] = x @ [Wq;Wk;Wv]^T + b    768 blocks, 128x128x32, PIPE2
    gemm16<128, 32, 1, 2, false, 4, false, u16><<<dim3(12, 64, 1), blk, 0, stream>>>(
        x16, Wqkv16, bqkv, qk, vt, nullptr, 512, 512, 512, 1024, 0, 0, 0);
    // P'[b] = exp(q@k^T - m_b) -> fp16 + mb + sb   1024 blocks, 128x128x32, PIPE2
    gemm16<128, 32, 1, 2, false, 5, false, u16><<<dim3(16, 16, 4), blk, 0, stream>>>(
        qk, qk + 512, nullptr, p16, mb, sb, 512, 1024, 1024, 2048,
        2048L * 1024, 2048L * 1024, 2048L * 2048);
    // per-row softmax coefficients (transposed)              32 blocks
    softmax_stats<<<dim3(32), blk, 0, stream>>>(mb, sb, cf);
    // attn[b] = sum_cb coef * (P'_cb @ V_cb)      256 blocks, 128x128x64, splitK=2, T=16
    gemm16<128, 64, 2, 2, false, 2, true, u16><<<dim3(4, 16, 4), blk2, 0, stream>>>(
        p16, vt, nullptr, attn, nullptr, cf, 2048, 2048, 2048, 512,
        2048L * 2048, 512L * 2048, 2048L * 512);
    // h = relu(attn @ W1^T + b1)                  1024 blocks, 128x128x32, PIPE2
    gemm16<128, 32, 1, 2, true, 2, false, u16><<<dim3(16, 64, 1), blk, 0, stream>>>(
        attn, W116, b1, h, nullptr, nullptr, 512, 512, 512, 2048, 0, 0, 0);
    // out = h @ W2^T + b2                          256 blocks, 128x128x64, splitK=2, T=16
    gemm16<128, 64, 2, 2, false, 0, false, float><<<dim3(4, 64, 1), blk2, 0, stream>>>(
        h, W216, b2, out, nullptr, nullptr, 2048, 2048, 2048, 512, 0, 0, 0);
}

// Round 25
// 160.848 us; speedup vs baseline: 1.2307x; 1.0030x over previous
//
#include <hip/hip_runtime.h>
#include <hip/hip_bf16.h>

typedef _Float16  f16x8  __attribute__((ext_vector_type(8)));
typedef float     f32x4  __attribute__((ext_vector_type(4)));
typedef unsigned short u16;
typedef u16       u16x4  __attribute__((ext_vector_type(4)));
typedef u16       u16x8  __attribute__((ext_vector_type(8)));

__device__ __forceinline__ u16 f2h_bits(float f) {
    union { _Float16 h; u16 u; } v; v.h = (_Float16)f; return v.u;
}

template<int N> __device__ __forceinline__ void vmwait() {
    if constexpr (N == 0)      asm volatile("s_waitcnt vmcnt(0)" ::: "memory");
    else if constexpr (N == 3) asm volatile("s_waitcnt vmcnt(3)" ::: "memory");
    else if constexpr (N == 4) asm volatile("s_waitcnt vmcnt(4)" ::: "memory");
    else if constexpr (N == 6) asm volatile("s_waitcnt vmcnt(6)" ::: "memory");
    else if constexpr (N == 8) asm volatile("s_waitcnt vmcnt(8)" ::: "memory");
}
__device__ __forceinline__ void pipe_barrier() {
    __builtin_amdgcn_s_barrier();
    __builtin_amdgcn_sched_barrier(0);
}

// ALL fp32->fp16 conversions (x + Wq|Wk|Wv stacked + W1 + W2) + bias concat, ONE dispatch.
__global__ __launch_bounds__(256)
void cvt_all(const float* __restrict__ x,
             const float* __restrict__ Wq, const float* __restrict__ Wk,
             const float* __restrict__ Wv, const float* __restrict__ W1,
             const float* __restrict__ W2, const float* __restrict__ bq,
             const float* __restrict__ bk, const float* __restrict__ bv,
             u16* __restrict__ x16, u16* __restrict__ Wqkv16,
             u16* __restrict__ W116, u16* __restrict__ W216, float* __restrict__ bqkv) {
    const int i = blockIdx.x * 256 + threadIdx.x;
    constexpr int X4 = 8192 * 512 / 4;
    constexpr int S = 512 * 512 / 4, L = 2048 * 512 / 4;
    const float* src; u16* dst; int j;
    if      (i < X4)                 { src = x;  dst = x16;            j = i;                  }
    else if (i < X4 + S)             { src = Wq; dst = Wqkv16;         j = i - X4;             }
    else if (i < X4 + 2 * S)         { src = Wk; dst = Wqkv16 + 4 * S; j = i - X4 - S;         }
    else if (i < X4 + 3 * S)         { src = Wv; dst = Wqkv16 + 8 * S; j = i - X4 - 2 * S;     }
    else if (i < X4 + 3 * S + L)     { src = W1; dst = W116;           j = i - X4 - 3 * S;     }
    else if (i < X4 + 3 * S + 2 * L) { src = W2; dst = W216;           j = i - X4 - 3 * S - L; }
    else if (i < X4 + 3 * S + 2 * L + 384) {
        const int g = (i - X4 - 3 * S - 2 * L) * 4;
#pragma unroll
        for (int t = 0; t < 4; ++t) {
            const int e = g + t;
            bqkv[e] = (e < 512) ? bq[e] : (e < 1024 ? bk[e - 512] : bv[e - 1024]);
        }
        return;
    } else return;
    f32x4 v = ((const f32x4*)src)[j];
    u16x4 h;
#pragma unroll
    for (int t = 0; t < 4; ++t) h[t] = f2h_bits(v[t]);
    ((u16x4*)dst)[j] = h;
}

// Stage a ROWSxCOLS 16-bit tile into LDS [ROWS][COLS] via global_load_lds dwordx4, with
// bank-conflict XOR swizzle applied via the GLOBAL source (LDS dest linear; rule 21).
// COLS=32: chunk cp of row holds global chunk cp^((row>>1)&3). COLS=64: cp^(row&7).
// NW waves cooperate.
template<int ROWS, int COLS, int NW>
__device__ __forceinline__ void stage_rows(const u16* __restrict__ g0, int ld, u16* lds, int wl) {
    const int l = threadIdx.x & 63;
    constexpr int CH = ROWS * COLS * 2 / 1024 / NW;
#pragma unroll
    for (int i = 0; i < CH; ++i) {
        const int base = (wl * CH + i) << 10;
        const int off  = base + (l << 4);
        const int row  = off / (COLS * 2);
        const int cp   = (off >> 4) & (COLS / 8 - 1);
        const int cs   = (COLS == 32) ? (cp ^ ((row >> 1) & 3)) : (cp ^ (row & 7));
        const u16* g = g0 + (size_t)row * ld + cs * 8;
        __builtin_amdgcn_global_load_lds((const __attribute__((address_space(1))) void*)g,
                                         (__attribute__((address_space(3))) void*)((char*)lds + base),
                                         16, 0, 0);
    }
}

// Swizzled fragment read: logical chunk lc of row lives at swizzled LDS chunk.
template<int COLS>
__device__ __forceinline__ f16x8 frag_read(const u16* tile, int row, int lc) {
    if constexpr (COLS == 32)
        return *(const f16x8*)&tile[row * 32 + ((lc ^ ((row >> 1) & 3)) << 3)];
    else
        return *(const f16x8*)&tile[row * 64 + ((lc ^ (row & 7)) << 3)];
}

// C[M,N] = A[M,K] @ B[N,K]^T (+bias). fp16 operands, fp32 accumulate.
// BM=128, BN in {64,128}, BK in {32,64}. PIPE=2: 2-slot dbuf + syncthreads.
// PIPE=3: 3-slot pipeline, counted vmcnt(LPT) + raw barrier (T3/T4).
// SPLITK=2: waves [0,4) K/2-low, [4,8) K/2-high (own slots), LDS-reduce at end.
// PVS: A is unnormalized P' = exp(s - m_b). Prologue: threads 0-127 each compute this
//      block's 128 rows' softmax coefs coef=exp(mb-m)/Z from mb (xtra) / sb (xtra2)
//      into LDS cfs[cb][row] (fused softmax_stats). Per 64-K chunk fold tmp into acc
//      scaled by cfs (broadcast LDS read at chunk start).
// OMODE: 0 fp32 out; 2 fp16 out; 4 fused QKV (qk linear n<1024, vt transposed n>=1024);
//        5 P' fp16 out + per-(row,64col) max (xtra) and sumexp (xtra2).
template<int BN, int BK, int SPLITK, int PIPE, bool RELU, int OMODE, bool PVS, typename TC>
__global__ __launch_bounds__(256 * SPLITK,
                             (SPLITK == 2 && (BK == 64 || (PIPE == 3 && BN == 128))) ? 2
                                                                                    : 2 * SPLITK)
void gemm16(const u16* __restrict__ Ag, const u16* __restrict__ Bg,
            const float* __restrict__ bias, TC* __restrict__ C,
            void* __restrict__ xtra, const void* __restrict__ xtra2,
            int K, int lda, int ldb, int ldc,
            long sA, long sB, long sC)
{
    // XCD-aware bijective swizzle (all grids have nwg % 8 == 0).
    const int nx = gridDim.x, ny = gridDim.y;
    const int nwg = nx * ny * gridDim.z;
    int bid = blockIdx.x + nx * (blockIdx.y + ny * blockIdx.z);
    int swz = (bid & 7) * (nwg >> 3) + (bid >> 3);
    const int n0 = (swz % nx) * BN; swz /= nx;
    const int m0 = (swz % ny) * 128;
    const int bz = swz / ny;

    constexpr int FR = (BN == 128) ? 4 : 2;      // 16-row A-fragments per wave
    constexpr int ATILE = 128 * BK;
    constexpr int BTILE = BN * BK;
    constexpr int BUFSZ = ATILE + BTILE;
    constexpr int LPT = (128 + BN) * BK * 2 / 1024 / 4;  // gloads per thread per tile
    __shared__ __align__(16) u16 smem[SPLITK * PIPE * BUFSZ];
    __shared__ float cfs[PVS ? 32 : 1][PVS ? 128 : 1];   // fused softmax coefs

    const int l  = threadIdx.x & 63, w = threadIdx.x >> 6;
    const int kw = (SPLITK == 2) ? (w >> 2) : 0;
    const int wl = w & 3;
    const int wr = (BN == 128) ? (wl >> 1) * 64 : wl * 32;
    const int wc = (BN == 128) ? (wl & 1) * 64 : 0;
    const int lr = l & 15, kg = l >> 4;

    const int Kh = K / SPLITK;
    const int kb = kw * Kh;
    const int T  = Kh / BK;

    const u16* Ab = Ag + (size_t)bz * sA + (size_t)m0 * lda + kb;
    const u16* Bb = Bg + (size_t)bz * sB + (size_t)n0 * ldb + kb;
    C += (size_t)bz * sC;

    u16* mybuf = smem + kw * PIPE * BUFSZ;

    // Fused softmax stats: each of threads 0-127 computes one row's 32 coefs into LDS.
    if constexpr (PVS) {
        const int tid = threadIdx.x;
        if (tid < 128) {
            const float* mbp = (const float*)xtra  + ((size_t)bz * 2048 + (m0 + tid)) * 32;
            const float* sbp = (const float*)xtra2 + ((size_t)bz * 2048 + (m0 + tid)) * 32;
            f32x4 mv[8], sv[8];
#pragma unroll
            for (int i = 0; i < 8; ++i) { mv[i] = ((const f32x4*)mbp)[i]; sv[i] = ((const f32x4*)sbp)[i]; }
            float m = mv[0][0];
#pragma unroll
            for (int i = 0; i < 8; ++i)
#pragma unroll
                for (int j = 0; j < 4; ++j) m = fmaxf(m, mv[i][j]);
            float e[8][4]; float s = 0.0f;
#pragma unroll
            for (int i = 0; i < 8; ++i)
#pragma unroll
                for (int j = 0; j < 4; ++j) { e[i][j] = __expf(mv[i][j] - m); s += sv[i][j] * e[i][j]; }
            const float inv = 1.0f / s;
#pragma unroll
            for (int i = 0; i < 8; ++i)
#pragma unroll
                for (int j = 0; j < 4; ++j) cfs[i * 4 + j][tid] = e[i][j] * inv;
        }
    }

    auto stage = [&](int slot, int t) {
        u16* s = mybuf + slot * BUFSZ;
        stage_rows<128, BK, 4>(Ab + t * BK, lda, s, wl);
        stage_rows<BN, BK, 4>(Bb + t * BK, ldb, s + ATILE, wl);
    };

    f32x4 acc[FR][4] = {};
    f32x4 tmp[FR][4] = {};
    f32x4 cfp[FR];
    auto compute = [&](int slot) {
        const u16* sA = mybuf + slot * BUFSZ;
        const u16* sB = sA + ATILE;
        constexpr int NSUB = BK / 32;
#pragma unroll
        for (int sub = 0; sub < NSUB; ++sub) {
            f16x8 a[FR], b[4];
#pragma unroll
            for (int i = 0; i < FR; ++i) a[i] = frag_read<BK>(sA, wr + i * 16 + lr, sub * 4 + kg);
#pragma unroll
            for (int i = 0; i < 4; ++i)  b[i] = frag_read<BK>(sB, wc + i * 16 + lr, sub * 4 + kg);
#pragma unroll
            for (int mi = 0; mi < FR; ++mi)
#pragma unroll
                for (int ni = 0; ni < 4; ++ni) {
                    if constexpr (PVS)
                        tmp[mi][ni] = __builtin_amdgcn_mfma_f32_16x16x32_f16(a[mi], b[ni], tmp[mi][ni], 0, 0, 0);
                    else
                        acc[mi][ni] = __builtin_amdgcn_mfma_f32_16x16x32_f16(a[mi], b[ni], acc[mi][ni], 0, 0, 0);
                }
        }
    };
    auto pvs_pre = [&](int t) {
        if constexpr (PVS) {
            if (BK == 64 || (t & 1) == 0) {      // 64-K chunk start: broadcast LDS read
                const int cb = (kb + t * BK) >> 6;
#pragma unroll
                for (int mi = 0; mi < FR; ++mi)
                    cfp[mi] = *(const f32x4*)&cfs[cb][wr + mi * 16 + kg * 4];
            }
        }
    };
    auto pvs_post = [&](int t) {
        if constexpr (PVS) {
            if (BK == 64 || (t & 1)) {           // 64-K chunk end: fold with coef
#pragma unroll
                for (int mi = 0; mi < FR; ++mi)
#pragma unroll
                    for (int ni = 0; ni < 4; ++ni) {
#pragma unroll
                        for (int j = 0; j < 4; ++j) acc[mi][ni][j] += cfp[mi][j] * tmp[mi][ni][j];
                        tmp[mi][ni] = f32x4{0.f, 0.f, 0.f, 0.f};
                    }
            }
        }
    };

    if constexpr (PIPE == 3) {
        stage(0, 0);
        stage(1, 1);
        vmwait<LPT>();                           // tile 0 resident, tile 1 in flight
        pipe_barrier();
        for (int t = 0; t < T; ++t) {
            pvs_pre(t);
            if (t + 2 < T) stage((t + 2) % 3, t + 2);
            compute(t % 3);
            pvs_post(t);
            if (t + 2 < T) vmwait<LPT>();        // tile t+1 resident, t+2 in flight
            else           vmwait<0>();
            pipe_barrier();
        }
    } else {
        stage(0, 0);
        __syncthreads();                          // covers cfs prologue too
        int cur = 0;
        for (int t = 0; t < T; ++t) {
            if (t + 1 < T) stage(cur ^ 1, t + 1);
            pvs_pre(t);
            compute(cur);
            pvs_post(t);
            __syncthreads();
            cur ^= 1;
        }
    }

    if constexpr (SPLITK == 2) {
        float* red = (float*)smem;
        const int slot = (wl * 64 + l) * (FR * 4);
        if (kw == 1) {
#pragma unroll
            for (int mi = 0; mi < FR; ++mi)
#pragma unroll
                for (int ni = 0; ni < 4; ++ni)
                    *(f32x4*)&red[(slot + mi * 4 + ni) * 4] = acc[mi][ni];
        }
        __syncthreads();
        if (kw == 1) return;
#pragma unroll
        for (int mi = 0; mi < FR; ++mi)
#pragma unroll
            for (int ni = 0; ni < 4; ++ni)
                acc[mi][ni] += *(const f32x4*)&red[(slot + mi * 4 + ni) * 4];
    }

    if constexpr (OMODE == 5) {
        float* MB = (float*)xtra + (size_t)bz * 2048 * 32;
        float* SB = (float*)const_cast<void*>(xtra2);
        SB += (size_t)bz * 2048 * 32;
        const int cb = (n0 + wc) >> 6;
#pragma unroll
        for (int mi = 0; mi < FR; ++mi) {
            const int mbase = m0 + wr + mi * 16 + kg * 4;
#pragma unroll
            for (int j = 0; j < 4; ++j) {
                float rmax = fmaxf(fmaxf(acc[mi][0][j], acc[mi][1][j]),
                                   fmaxf(acc[mi][2][j], acc[mi][3][j]));
                rmax = fmaxf(rmax, __shfl_xor(rmax, 1));
                rmax = fmaxf(rmax, __shfl_xor(rmax, 2));
                rmax = fmaxf(rmax, __shfl_xor(rmax, 4));
                rmax = fmaxf(rmax, __shfl_xor(rmax, 8));
                float p[4]; float lsum = 0.0f;
#pragma unroll
                for (int ni = 0; ni < 4; ++ni) { p[ni] = __expf(acc[mi][ni][j] - rmax); lsum += p[ni]; }
                lsum += __shfl_xor(lsum, 1);
                lsum += __shfl_xor(lsum, 2);
                lsum += __shfl_xor(lsum, 4);
                lsum += __shfl_xor(lsum, 8);
                const int row = mbase + j;
                if (lr == 0) {
                    MB[(size_t)row * 32 + cb] = rmax;
                    SB[(size_t)row * 32 + cb] = lsum;
                }
#pragma unroll
                for (int ni = 0; ni < 4; ++ni)
                    ((u16*)C)[(size_t)row * ldc + (n0 + wc + ni * 16 + lr)] = f2h_bits(p[ni]);
            }
        }
        return;
    }

#pragma unroll
    for (int mi = 0; mi < FR; ++mi) {
        const int mbase = m0 + wr + mi * 16 + kg * 4;
#pragma unroll
        for (int ni = 0; ni < 4; ++ni) {
            const int n = n0 + wc + ni * 16 + lr;
            const float bv = bias ? bias[n] : 0.0f;
            if constexpr (OMODE == 4) {
                if (n0 < 1024) {        // q|k region, fp16 linear [8192][1024]
#pragma unroll
                    for (int j = 0; j < 4; ++j)
                        ((u16*)C)[(size_t)(mbase + j) * ldc + n] = f2h_bits(acc[mi][ni][j] + bv);
                } else {                // v region, transposed vt[4][512][2048]
                    const int d  = n - 1024;
                    const int bb = mbase >> 11;
                    const int s  = mbase & 2047;
                    u16x4 o;
#pragma unroll
                    for (int j = 0; j < 4; ++j) o[j] = f2h_bits(acc[mi][ni][j] + bv);
                    *(u16x4*)((u16*)xtra + ((size_t)bb * 512 + d) * 2048 + s) = o;
                }
            } else {
#pragma unroll
                for (int j = 0; j < 4; ++j) {
                    float x = acc[mi][ni][j] + bv;
                    if constexpr (RELU) x = fmaxf(x, 0.0f);
                    const size_t idx = (size_t)(mbase + j) * ldc + n;
                    if constexpr (OMODE == 0) C[idx] = x;
                    else                      ((u16*)C)[idx] = f2h_bits(x);
                }
            }
        }
    }
}

extern "C" void kernel_launch(void* const* d_in, const int* in_sizes, int n_in,
                              void* d_out, int out_size, void* d_ws, size_t ws_size,
                              hipStream_t stream) {
    const float* x  = (const float*)d_in[0];
    const float* Wq = (const float*)d_in[1];
    const float* bq = (const float*)d_in[2];
    const float* Wk = (const float*)d_in[3];
    const float* bk = (const float*)d_in[4];
    const float* Wv = (const float*)d_in[5];
    const float* bv = (const float*)d_in[6];
    const float* W1 = (const float*)d_in[7];
    const float* b1 = (const float*)d_in[8];
    const float* W2 = (const float*)d_in[9];
    const float* b2 = (const float*)d_in[10];
    float* out = (float*)d_out;

    char* ws = (char*)d_ws;
    size_t off = 0;
    auto alloc = [&](size_t bytes) { void* p = ws + off; off += (bytes + 255) & ~(size_t)255; return p; };
    u16* x16    = (u16*)alloc(8192ull * 512 * 2);        //  8.4 MB; attn overlays later
    u16* Wqkv16 = (u16*)alloc(1536ull * 512 * 2);
    u16* W116   = (u16*)alloc(2048ull * 512 * 2);
    u16* W216   = (u16*)alloc(512ull * 2048 * 2);
    float* bqkv = (float*)alloc(1536 * 4);
    u16* qk     = (u16*)alloc(8192ull * 1024 * 2);       // 16.8 MB fp16 [8192][1024]
    u16* p16    = (u16*)alloc(4ull * 2048 * 2048 * 2);   // 33.6 MB unnormalized P'; h overlays
    u16* vt     = (u16*)alloc(4ull * 512 * 2048 * 2);    //  8.4 MB fp16 [b][d][s]
    float* mb   = (float*)alloc(8192ull * 32 * 4);       //  1 MB per-(row,64col) max
    float* sb   = (float*)alloc(8192ull * 32 * 4);       //  1 MB per-(row,64col) sumexp
    u16* attn = x16;                    // fp16 [8192][512]; x dead after projections
    u16* h    = p16;                    // fp16 [8192][2048]; P' dead after PV
    if (ws_size < off) return;

    dim3 blk(256), blk2(512);

    cvt_all<<<dim3(6914), blk, 0, stream>>>(x, Wq, Wk, Wv, W1, W2, bq, bk, bv,
                                            x16, Wqkv16, W116, W216, bqkv);

    // [q|k|vt] = x @ [Wq;Wk;Wv]^T + b    768 blocks, 128x128x32, PIPE2
    gemm16<128, 32, 1, 2, false, 4, false, u16><<<dim3(12, 64, 1), blk, 0, stream>>>(
        x16, Wqkv16, bqkv, qk, vt, nullptr, 512, 512, 512, 1024, 0, 0, 0);
    // P'[b] = exp(q@k^T - m_b) -> fp16 + mb + sb   1024 blocks, 128x128x32, PIPE2
    gemm16<128, 32, 1, 2, false, 5, false, u16><<<dim3(16, 16, 4), blk, 0, stream>>>(
        qk, qk + 512, nullptr, p16, mb, sb, 512, 1024, 1024, 2048,
        2048L * 1024, 2048L * 1024, 2048L * 2048);
    // attn[b] = sum_cb coef * (P'_cb @ V_cb), coefs fused in prologue from mb/sb
    //                                              256 blocks, 128x128x64, splitK=2, T=16
    gemm16<128, 64, 2, 2, false, 2, true, u16><<<dim3(4, 16, 4), blk2, 0, stream>>>(
        p16, vt, nullptr, attn, mb, sb, 2048, 2048, 2048, 512,
        2048L * 2048, 512L * 2048, 2048L * 512);
    // h = relu(attn @ W1^T + b1)                  1024 blocks, 128x128x32, PIPE2
    gemm16<128, 32, 1, 2, true, 2, false, u16><<<dim3(16, 64, 1), blk, 0, stream>>>(
        attn, W116, b1, h, nullptr, nullptr, 512, 512, 512, 2048, 0, 0, 0);
    // out = h @ W2^T + b2                          256 blocks, 128x128x64, splitK=2, T=16
    gemm16<128, 64, 2, 2, false, 0, false, float><<<dim3(4, 64, 1), blk2, 0, stream>>>(
        h, W216, b2, out, nullptr, nullptr, 2048, 2048, 2048, 512, 0, 0, 0);
}